// Round 6
// baseline (230.123 us; speedup 1.0000x reference)
//
#include <hip/hip_runtime.h>
#include <hip/hip_bf16.h>

// Gaussian upsampler: B=16, N=512, D=256, T derived from out_size.
// Outputs (flat): positions [B,T] (f32), out [B,T,D], weights [B,N,T].
//
// Structure (R6): scan (cumsum/centers) -> pass1 (positions + iw2 + out1 via
// bf16 MFMA per 64-frame tile; waves split the D dimension) -> weights
// (contiguous streaming rows, zeros outside the f32-exact underflow band).
// R6 delta vs R5: nontemporal stores ONLY on weights_kernel's aligned f32x4
// streams (write-once full lines; R4 showed NT on pass1's scalar partial-line
// epilogue stores regresses, so those stay cached).
//
// Locality: ranges <= 4.0 and f32 expf underflows to 0 for |t-c| >= 10.3*r
// (arg <= -106 < ln(2^-149)). Durations >= 4 => a 64-frame tile + 2*42 margin
// spans <= 38 tokens; window cap 44, K-padded to 64 for MFMA.

#define TT  64       // frames per tile (pass 1)
#define NWC 44       // max valid window tokens
#define WBS 72       // wb bf16 row stride (144 B = 9*16: aligned b128 rows)
#define MARGIN 42.0f
#define RPB 4        // weight rows per block (pass 2)

typedef __attribute__((ext_vector_type(8))) short short8;
typedef __attribute__((ext_vector_type(8))) unsigned short ushort8;
typedef __attribute__((ext_vector_type(4))) float f32x4;

__device__ inline unsigned short f2bf(float f) {
    union { float f; unsigned int u; } v; v.f = f;
    unsigned int u = v.u;
    return (unsigned short)((u + 0x7FFFu + ((u >> 16) & 1u)) >> 16);  // RNE
}

__global__ void scan_kernel(const int* __restrict__ dur,
                            const float* __restrict__ ranges,
                            float* __restrict__ c, float* __restrict__ ir,
                            int* __restrict__ e_i, int* __restrict__ st_i) {
    const int N = 512;
    int b = blockIdx.x, tid = threadIdx.x;
    __shared__ int sc[512];
    int d = dur[b * N + tid];
    sc[tid] = d;
    __syncthreads();
    for (int off = 1; off < 512; off <<= 1) {
        int add = (tid >= off) ? sc[tid - off] : 0;
        __syncthreads();
        sc[tid] += add;
        __syncthreads();
    }
    int e = sc[tid];
    float r = ranges[b * N + tid];
    c[b * N + tid]    = (float)e - 0.5f * (float)d;
    ir[b * N + tid]   = 1.0f / (r * r);
    e_i[b * N + tid]  = e;
    st_i[b * N + tid] = e - d;
}

// Pass 1: per (b, 64-frame tile): positions, iw2 -> ws, out1 via MFMA.
__global__ __launch_bounds__(256) void pass1_kernel(
        const float* __restrict__ x, const float* __restrict__ c,
        const float* __restrict__ ir,
        const int* __restrict__ e_i, const int* __restrict__ st_i,
        float* __restrict__ pos_out /*[B,T]*/,
        float* __restrict__ out1 /*[B,T,D]*/,
        float* __restrict__ iw2_ws /*[B,T]*/,
        int T) {
    const int N = 512, D = 256;
    int b = blockIdx.y;
    int t0 = blockIdx.x * TT;
    int tid = threadIdx.x;

    __shared__ float c_s[512];
    __shared__ float ir_s[512];
    __shared__ int   es[512], ss[512];
    __shared__ __align__(16) unsigned short wb[TT][WBS]; // bf16 w1, K-padded
    __shared__ float part[4][TT];
    __shared__ float iw2_s[TT];
    __shared__ int lohi[2];

    for (int i = tid; i < 512; i += 256) {
        c_s[i]  = c[b * N + i];
        ir_s[i] = ir[b * N + i];
        es[i]   = e_i[b * N + i];
        ss[i]   = st_i[b * N + i];
    }
    __syncthreads();

    if (tid == 0) {
        float lo_v = (float)t0 - MARGIN;
        float hi_v = (float)(t0 + TT - 1) + MARGIN;
        int lo = 0, hi = 512;
        while (lo < hi) { int m = (lo + hi) >> 1; if (c_s[m] < lo_v) lo = m + 1; else hi = m; }
        int l = lo;
        lo = 0; hi = 512;
        while (lo < hi) { int m = (lo + hi) >> 1; if (c_s[m] <= hi_v) lo = m + 1; else hi = m; }
        int h = lo - 1;
        if (h > l + NWC - 1) h = l + NWC - 1;   // unreachable for dur>=4
        lohi[0] = l; lohi[1] = h;
    }
    // positions: one thread per tile frame
    if (tid < TT) {
        int t = t0 + tid;
        if (t < T) {
            int lo = 0, hi = 512;
            while (lo < hi) { int m = (lo + hi) >> 1; if (es[m] <= t) lo = m + 1; else hi = m; }
            int seg = min(lo, 511);
            pos_out[b * T + t] = (float)(t - ss[seg]);
        }
    }
    __syncthreads();
    int lo_u = lohi[0], hi_u = lohi[1];

    int tl = tid & 63;          // frame within tile
    int s  = tid >> 6;          // wave id
    int t  = t0 + tl;

    // Phase A: Gaussians for window (K-padded to 64), bf16 into wb, w2 partials
    float p = 0.f;
    #pragma unroll
    for (int jj = 0; jj < 16; jj++) {
        int i = s + 4 * jj;
        int n = lo_u + i;
        float w1 = 0.f;
        if (n <= hi_u && t < T) {
            float d = (float)t - c_s[n];
            w1 = expf(-ir_s[n] * d * d);    // underflows to 0 exactly like f32 ref
        }
        wb[tl][i] = f2bf(w1);
        p += w1;
    }
    part[s][tl] = p;
    __syncthreads();
    if (tid < TT) {
        float w2 = part[0][tid] + part[1][tid] + part[2][tid] + part[3][tid];
        float iw2 = 1.0f / (w2 + 1e-20f);
        iw2_s[tid] = iw2;
        int t2 = t0 + tid;
        if (t2 < T) iw2_ws[b * T + t2] = iw2;   // re-read by weights_kernel
    }
    __syncthreads();

    // Phase C: MFMA. C[64t x 256d] = W[64 x 64] @ X[64 x 256].
    // Wave s owns d-slice [64s, 64s+64): bfrag built once per (ks,nt),
    // reused across 4 m-tiles => 64 gather loads + 64 f2bf per thread.
    int lane = tid & 63;
    int l15  = lane & 15;
    int q    = lane >> 4;

    f32x4 acc[4][4];    // [mt][nt]
    #pragma unroll
    for (int mt = 0; mt < 4; mt++)
        #pragma unroll
        for (int nt = 0; nt < 4; nt++)
            acc[mt][nt] = (f32x4){0.f, 0.f, 0.f, 0.f};

    const float* xb = x + (size_t)b * N * D;
    #pragma unroll
    for (int ks = 0; ks < 2; ks++) {
        const float* rp[8];
        #pragma unroll
        for (int j = 0; j < 8; j++) {
            int tok = lo_u + ks * 32 + q * 8 + j;
            tok = min(tok, 511);            // OOB rows multiply w1==0
            rp[j] = xb + (size_t)tok * D;
        }
        short8 afrag[4];
        #pragma unroll
        for (int mt = 0; mt < 4; mt++)
            afrag[mt] = *(const short8*)&wb[16 * mt + l15][ks * 32 + q * 8];
        #pragma unroll
        for (int nt = 0; nt < 4; nt++) {
            int d = 64 * s + nt * 16 + l15;
            ushort8 bu;
            #pragma unroll
            for (int j = 0; j < 8; j++) bu[j] = f2bf(rp[j][d]);
            short8 bfrag = (short8)bu;
            #pragma unroll
            for (int mt = 0; mt < 4; mt++)
                acc[mt][nt] = __builtin_amdgcn_mfma_f32_16x16x32_bf16(afrag[mt], bfrag, acc[mt][nt], 0, 0, 0);
        }
    }

    // Epilogue: C row = 16*mt + q*4 + r, cols 64s + nt*16 + l15 (cached stores)
    #pragma unroll
    for (int mt = 0; mt < 4; mt++) {
        #pragma unroll
        for (int r = 0; r < 4; r++) {
            int tt = t0 + 16 * mt + q * 4 + r;
            if (tt < T) {
                float iw2 = iw2_s[16 * mt + q * 4 + r];
                float* orow = out1 + ((size_t)b * T + tt) * D + 64 * s;
                #pragma unroll
                for (int nt = 0; nt < 4; nt++)
                    orow[nt * 16 + l15] = acc[mt][nt][r] * iw2;
            }
        }
    }
}

// Pass 2: stream weights rows contiguously. Block = (b, RPB consecutive n).
// Aligned f32x4 stores are nontemporal: write-once full lines, keep L2 for x.
__global__ __launch_bounds__(256) void weights_kernel(
        const float* __restrict__ c, const float* __restrict__ ir,
        const float* __restrict__ iw2_ws,
        float* __restrict__ out2 /*[B,N,T]*/, int T) {
    const int N = 512;
    int b = blockIdx.y;
    int n0 = blockIdx.x * RPB;
    int tid = threadIdx.x;
    const f32x4 z4 = (f32x4){0.f, 0.f, 0.f, 0.f};

    for (int r = 0; r < RPB; r++) {
        int n = n0 + r;
        float cn  = c[b * N + n];
        float irn = ir[b * N + n];
        float rad = 10.3f * __frsqrt_rn(irn) + 1.0f;  // outside => expf==0 in f32
        int lo = (int)(cn - rad); if (lo < 0) lo = 0;
        int hi = (int)(cn + rad) + 1; if (hi > T) hi = T;   // nonzero only in [lo, hi)

        size_t base = ((size_t)b * N + n) * (size_t)T;
        int head = (int)((4 - (base & 3)) & 3);             // floats to 16B alignment
        if (head > T) head = T;
        if (tid < head) {
            int t = tid;
            float w = 0.f;
            if (t >= lo && t < hi) {
                float d = (float)t - cn;
                w = expf(-irn * d * d) * iw2_ws[b * T + t];
            }
            out2[base + t] = w;
        }
        int ngrp = (T - head) >> 2;
        int tail = (T - head) & 3;
        float* rowp = (float*)(out2 + base + head);
        for (int g = tid; g < ngrp; g += 256) {
            int tg = head + 4 * g;
            f32x4 v = z4;
            if (tg + 3 >= lo && tg < hi) {
                #pragma unroll
                for (int k = 0; k < 4; k++) {
                    int t = tg + k;
                    if (t >= lo && t < hi) {
                        float d = (float)t - cn;
                        v[k] = expf(-irn * d * d) * iw2_ws[b * T + t];
                    }
                }
            }
            __builtin_nontemporal_store(v, (f32x4*)(rowp + 4 * g));
        }
        if (tid < tail) {
            int t = head + 4 * ngrp + tid;
            float w = 0.f;
            if (t >= lo && t < hi) {
                float d = (float)t - cn;
                w = expf(-irn * d * d) * iw2_ws[b * T + t];
            }
            out2[base + t] = w;
        }
    }
}

extern "C" void kernel_launch(void* const* d_in, const int* in_sizes, int n_in,
                              void* d_out, int out_size, void* d_ws, size_t ws_size,
                              hipStream_t stream) {
    const float* x      = (const float*)d_in[0];
    const int*   dur    = (const int*)d_in[1];
    const float* ranges = (const float*)d_in[2];
    const int B = 16, N = 512, D = 256;
    const int T = out_size / (B * (1 + D + N));

    float* pos_out = (float*)d_out;
    float* out1    = pos_out + (size_t)B * T;
    float* out2    = out1 + (size_t)B * T * D;

    float* c      = (float*)d_ws;
    float* ir     = c + B * N;
    int*   e_i    = (int*)(ir + B * N);
    int*   st_i   = e_i + B * N;
    float* iw2_ws = (float*)(st_i + B * N);

    scan_kernel<<<B, 512, 0, stream>>>(dur, ranges, c, ir, e_i, st_i);

    dim3 g1((T + TT - 1) / TT, B);
    pass1_kernel<<<g1, 256, 0, stream>>>(x, c, ir, e_i, st_i, pos_out, out1, iw2_ws, T);

    dim3 g2(N / RPB, B);
    weights_kernel<<<g2, 256, 0, stream>>>(c, ir, iw2_ws, out2, T);
}

// Round 7
// 219.445 us; speedup vs baseline: 1.0487x; 1.0487x over previous
//
#include <hip/hip_runtime.h>
#include <hip/hip_bf16.h>

// Gaussian upsampler: B=16, N=512, D=256, T derived from out_size.
// Outputs (flat): positions [B,T] (f32), out [B,T,D], weights [B,N,T].
//
// Structure (R7 == R5, the best-measured config at 220.4 us):
//   scan (cumsum/centers) -> pass1 (positions + iw2 + out1 via bf16 MFMA per
//   64-frame tile; waves split the D dimension) -> weights (contiguous
//   streaming rows, zeros outside the f32-exact underflow band).
// R7 delta vs R6: reverted nontemporal stores entirely. Two clean A/B tests
// (R4: +15 us, R6: +10 us) show NT stores consistently regress on gfx950 for
// these streaming writes — cached write-combined stores are the fast path.
//
// Locality: ranges <= 4.0 and f32 expf underflows to 0 for |t-c| >= 10.3*r
// (arg <= -106 < ln(2^-149)). Durations >= 4 => a 64-frame tile + 2*42 margin
// spans <= 38 tokens; window cap 44, K-padded to 64 for MFMA.

#define TT  64       // frames per tile (pass 1)
#define NWC 44       // max valid window tokens
#define WBS 72       // wb bf16 row stride (144 B = 9*16: aligned b128 rows)
#define MARGIN 42.0f
#define RPB 4        // weight rows per block (pass 2)

typedef __attribute__((ext_vector_type(8))) short short8;
typedef __attribute__((ext_vector_type(8))) unsigned short ushort8;
typedef __attribute__((ext_vector_type(4))) float f32x4;

__device__ inline unsigned short f2bf(float f) {
    union { float f; unsigned int u; } v; v.f = f;
    unsigned int u = v.u;
    return (unsigned short)((u + 0x7FFFu + ((u >> 16) & 1u)) >> 16);  // RNE
}

__global__ void scan_kernel(const int* __restrict__ dur,
                            const float* __restrict__ ranges,
                            float* __restrict__ c, float* __restrict__ ir,
                            int* __restrict__ e_i, int* __restrict__ st_i) {
    const int N = 512;
    int b = blockIdx.x, tid = threadIdx.x;
    __shared__ int sc[512];
    int d = dur[b * N + tid];
    sc[tid] = d;
    __syncthreads();
    for (int off = 1; off < 512; off <<= 1) {
        int add = (tid >= off) ? sc[tid - off] : 0;
        __syncthreads();
        sc[tid] += add;
        __syncthreads();
    }
    int e = sc[tid];
    float r = ranges[b * N + tid];
    c[b * N + tid]    = (float)e - 0.5f * (float)d;
    ir[b * N + tid]   = 1.0f / (r * r);
    e_i[b * N + tid]  = e;
    st_i[b * N + tid] = e - d;
}

// Pass 1: per (b, 64-frame tile): positions, iw2 -> ws, out1 via MFMA.
__global__ __launch_bounds__(256) void pass1_kernel(
        const float* __restrict__ x, const float* __restrict__ c,
        const float* __restrict__ ir,
        const int* __restrict__ e_i, const int* __restrict__ st_i,
        float* __restrict__ pos_out /*[B,T]*/,
        float* __restrict__ out1 /*[B,T,D]*/,
        float* __restrict__ iw2_ws /*[B,T]*/,
        int T) {
    const int N = 512, D = 256;
    int b = blockIdx.y;
    int t0 = blockIdx.x * TT;
    int tid = threadIdx.x;

    __shared__ float c_s[512];
    __shared__ float ir_s[512];
    __shared__ int   es[512], ss[512];
    __shared__ __align__(16) unsigned short wb[TT][WBS]; // bf16 w1, K-padded
    __shared__ float part[4][TT];
    __shared__ float iw2_s[TT];
    __shared__ int lohi[2];

    for (int i = tid; i < 512; i += 256) {
        c_s[i]  = c[b * N + i];
        ir_s[i] = ir[b * N + i];
        es[i]   = e_i[b * N + i];
        ss[i]   = st_i[b * N + i];
    }
    __syncthreads();

    if (tid == 0) {
        float lo_v = (float)t0 - MARGIN;
        float hi_v = (float)(t0 + TT - 1) + MARGIN;
        int lo = 0, hi = 512;
        while (lo < hi) { int m = (lo + hi) >> 1; if (c_s[m] < lo_v) lo = m + 1; else hi = m; }
        int l = lo;
        lo = 0; hi = 512;
        while (lo < hi) { int m = (lo + hi) >> 1; if (c_s[m] <= hi_v) lo = m + 1; else hi = m; }
        int h = lo - 1;
        if (h > l + NWC - 1) h = l + NWC - 1;   // unreachable for dur>=4
        lohi[0] = l; lohi[1] = h;
    }
    // positions: one thread per tile frame
    if (tid < TT) {
        int t = t0 + tid;
        if (t < T) {
            int lo = 0, hi = 512;
            while (lo < hi) { int m = (lo + hi) >> 1; if (es[m] <= t) lo = m + 1; else hi = m; }
            int seg = min(lo, 511);
            pos_out[b * T + t] = (float)(t - ss[seg]);
        }
    }
    __syncthreads();
    int lo_u = lohi[0], hi_u = lohi[1];

    int tl = tid & 63;          // frame within tile
    int s  = tid >> 6;          // wave id
    int t  = t0 + tl;

    // Phase A: Gaussians for window (K-padded to 64), bf16 into wb, w2 partials
    float p = 0.f;
    #pragma unroll
    for (int jj = 0; jj < 16; jj++) {
        int i = s + 4 * jj;
        int n = lo_u + i;
        float w1 = 0.f;
        if (n <= hi_u && t < T) {
            float d = (float)t - c_s[n];
            w1 = expf(-ir_s[n] * d * d);    // underflows to 0 exactly like f32 ref
        }
        wb[tl][i] = f2bf(w1);
        p += w1;
    }
    part[s][tl] = p;
    __syncthreads();
    if (tid < TT) {
        float w2 = part[0][tid] + part[1][tid] + part[2][tid] + part[3][tid];
        float iw2 = 1.0f / (w2 + 1e-20f);
        iw2_s[tid] = iw2;
        int t2 = t0 + tid;
        if (t2 < T) iw2_ws[b * T + t2] = iw2;   // re-read by weights_kernel
    }
    __syncthreads();

    // Phase C: MFMA. C[64t x 256d] = W[64 x 64] @ X[64 x 256].
    // Wave s owns d-slice [64s, 64s+64): bfrag built once per (ks,nt),
    // reused across 4 m-tiles => 64 gather loads + 64 f2bf per thread.
    int lane = tid & 63;
    int l15  = lane & 15;
    int q    = lane >> 4;

    f32x4 acc[4][4];    // [mt][nt]
    #pragma unroll
    for (int mt = 0; mt < 4; mt++)
        #pragma unroll
        for (int nt = 0; nt < 4; nt++)
            acc[mt][nt] = (f32x4){0.f, 0.f, 0.f, 0.f};

    const float* xb = x + (size_t)b * N * D;
    #pragma unroll
    for (int ks = 0; ks < 2; ks++) {
        const float* rp[8];
        #pragma unroll
        for (int j = 0; j < 8; j++) {
            int tok = lo_u + ks * 32 + q * 8 + j;
            tok = min(tok, 511);            // OOB rows multiply w1==0
            rp[j] = xb + (size_t)tok * D;
        }
        short8 afrag[4];
        #pragma unroll
        for (int mt = 0; mt < 4; mt++)
            afrag[mt] = *(const short8*)&wb[16 * mt + l15][ks * 32 + q * 8];
        #pragma unroll
        for (int nt = 0; nt < 4; nt++) {
            int d = 64 * s + nt * 16 + l15;
            ushort8 bu;
            #pragma unroll
            for (int j = 0; j < 8; j++) bu[j] = f2bf(rp[j][d]);
            short8 bfrag = (short8)bu;
            #pragma unroll
            for (int mt = 0; mt < 4; mt++)
                acc[mt][nt] = __builtin_amdgcn_mfma_f32_16x16x32_bf16(afrag[mt], bfrag, acc[mt][nt], 0, 0, 0);
        }
    }

    // Epilogue: C row = 16*mt + q*4 + r, cols 64s + nt*16 + l15
    #pragma unroll
    for (int mt = 0; mt < 4; mt++) {
        #pragma unroll
        for (int r = 0; r < 4; r++) {
            int tt = t0 + 16 * mt + q * 4 + r;
            if (tt < T) {
                float iw2 = iw2_s[16 * mt + q * 4 + r];
                float* orow = out1 + ((size_t)b * T + tt) * D + 64 * s;
                #pragma unroll
                for (int nt = 0; nt < 4; nt++)
                    orow[nt * 16 + l15] = acc[mt][nt][r] * iw2;
            }
        }
    }
}

// Pass 2: stream weights rows contiguously. Block = (b, RPB consecutive n).
__global__ __launch_bounds__(256) void weights_kernel(
        const float* __restrict__ c, const float* __restrict__ ir,
        const float* __restrict__ iw2_ws,
        float* __restrict__ out2 /*[B,N,T]*/, int T) {
    const int N = 512;
    int b = blockIdx.y;
    int n0 = blockIdx.x * RPB;
    int tid = threadIdx.x;
    const f32x4 z4 = (f32x4){0.f, 0.f, 0.f, 0.f};

    for (int r = 0; r < RPB; r++) {
        int n = n0 + r;
        float cn  = c[b * N + n];
        float irn = ir[b * N + n];
        float rad = 10.3f * __frsqrt_rn(irn) + 1.0f;  // outside => expf==0 in f32
        int lo = (int)(cn - rad); if (lo < 0) lo = 0;
        int hi = (int)(cn + rad) + 1; if (hi > T) hi = T;   // nonzero only in [lo, hi)

        size_t base = ((size_t)b * N + n) * (size_t)T;
        int head = (int)((4 - (base & 3)) & 3);             // floats to 16B alignment
        if (head > T) head = T;
        if (tid < head) {
            int t = tid;
            float w = 0.f;
            if (t >= lo && t < hi) {
                float d = (float)t - cn;
                w = expf(-irn * d * d) * iw2_ws[b * T + t];
            }
            out2[base + t] = w;
        }
        int ngrp = (T - head) >> 2;
        int tail = (T - head) & 3;
        float* rowp = (float*)(out2 + base + head);
        for (int g = tid; g < ngrp; g += 256) {
            int tg = head + 4 * g;
            f32x4 v = z4;
            if (tg + 3 >= lo && tg < hi) {
                #pragma unroll
                for (int k = 0; k < 4; k++) {
                    int t = tg + k;
                    if (t >= lo && t < hi) {
                        float d = (float)t - cn;
                        v[k] = expf(-irn * d * d) * iw2_ws[b * T + t];
                    }
                }
            }
            *(f32x4*)(rowp + 4 * g) = v;
        }
        if (tid < tail) {
            int t = head + 4 * ngrp + tid;
            float w = 0.f;
            if (t >= lo && t < hi) {
                float d = (float)t - cn;
                w = expf(-irn * d * d) * iw2_ws[b * T + t];
            }
            out2[base + t] = w;
        }
    }
}

extern "C" void kernel_launch(void* const* d_in, const int* in_sizes, int n_in,
                              void* d_out, int out_size, void* d_ws, size_t ws_size,
                              hipStream_t stream) {
    const float* x      = (const float*)d_in[0];
    const int*   dur    = (const int*)d_in[1];
    const float* ranges = (const float*)d_in[2];
    const int B = 16, N = 512, D = 256;
    const int T = out_size / (B * (1 + D + N));

    float* pos_out = (float*)d_out;
    float* out1    = pos_out + (size_t)B * T;
    float* out2    = out1 + (size_t)B * T * D;

    float* c      = (float*)d_ws;
    float* ir     = c + B * N;
    int*   e_i    = (int*)(ir + B * N);
    int*   st_i   = e_i + B * N;
    float* iw2_ws = (float*)(st_i + B * N);

    scan_kernel<<<B, 512, 0, stream>>>(dur, ranges, c, ir, e_i, st_i);

    dim3 g1((T + TT - 1) / TT, B);
    pass1_kernel<<<g1, 256, 0, stream>>>(x, c, ir, e_i, st_i, pos_out, out1, iw2_ws, T);

    dim3 g2(N / RPB, B);
    weights_kernel<<<g2, 256, 0, stream>>>(c, ir, iw2_ws, out2, T);
}